// Round 1
// baseline (3176.995 us; speedup 1.0000x reference)
//
#include <hip/hip_runtime.h>
#include <hip/hip_bf16.h>

// Problem: AdaConv2d — instance-norm -> per-sample grouped 3x3 conv ->
// grouped pointwise conv (fused into effective 3x3 weights) -> final
// dense 512->512 3x3 conv, all reflect-padded, f32.
// B=4, C=512, H=W=128, G=128 groups (4 ch/group).

#define HW 16384          // 128*128
#define NCH 512           // channels of x / ys / out
#define NBC 2048          // 4*512 (b,c) pairs

__device__ __forceinline__ int refl(int i) {
    // reflect padding (mode='reflect'), H=W=128, pad=1: -1 -> 1, 128 -> 126
    return i < 0 ? -i : (i > 127 ? 254 - i : i);
}

// ---------------- Kernel A: per-(b,c) mean / rstd -------------------------
__global__ __launch_bounds__(256) void stats_kernel(
        const float* __restrict__ x, float* __restrict__ mean,
        float* __restrict__ rstd) {
    int bc = blockIdx.x;                 // 0..2047
    const float4* p4 = (const float4*)(x + (size_t)bc * HW);
    float s = 0.f, ss = 0.f;
    for (int i = threadIdx.x; i < HW / 4; i += 256) {
        float4 v = p4[i];
        s  += v.x + v.y + v.z + v.w;
        ss += v.x * v.x + v.y * v.y + v.z * v.z + v.w * v.w;
    }
    // wave64 reduce
    for (int o = 32; o >= 1; o >>= 1) {
        s  += __shfl_down(s, o);
        ss += __shfl_down(ss, o);
    }
    __shared__ float sm[4], sm2[4];
    int wid = threadIdx.x >> 6, lane = threadIdx.x & 63;
    if (lane == 0) { sm[wid] = s; sm2[wid] = ss; }
    __syncthreads();
    if (threadIdx.x == 0) {
        float S = sm[0] + sm[1] + sm[2] + sm[3];
        float SS = sm2[0] + sm2[1] + sm2[2] + sm2[3];
        float m = S * (1.f / HW);
        float var = SS * (1.f / HW) - m * m;
        mean[bc] = m;
        rstd[bc] = rsqrtf(var + 1e-5f);
    }
}

// ---------------- Kernel B: effective grouped weights ---------------------
// we[b,g,c,kh,kw] = sum_m wp[b,g,m] * ws[b, g*4+m, c, kh, kw]
__global__ __launch_bounds__(256) void weff_kernel(
        const float* __restrict__ wsp, const float* __restrict__ wpw,
        float* __restrict__ we) {
    int idx = blockIdx.x * 256 + threadIdx.x;
    if (idx >= 4 * 128 * 4 * 9) return;
    int k = idx % 9;
    int c = (idx / 9) & 3;
    int g = (idx / 36) & 127;
    int b = idx / 4608;
    float acc = 0.f;
#pragma unroll
    for (int m = 0; m < 4; ++m) {
        acc += wpw[(b * 128 + g) * 4 + m] *
               wsp[(((size_t)b * 512 + g * 4 + m) * 4 + c) * 9 + k];
    }
    we[idx] = acc;
}

// ---------------- Kernel C: normalized grouped 3x3 conv ------------------
// ys[b*128+g, h, w] = bias[b,g] + sum_{c,k} we[b,g,c,k] * xn[b, g*4+c, ...]
__global__ __launch_bounds__(256) void midconv_kernel(
        const float* __restrict__ x, const float* __restrict__ mean,
        const float* __restrict__ rstd, const float* __restrict__ we,
        const float* __restrict__ bias, float* __restrict__ ys) {
    int bg = blockIdx.z;                  // b*128+g
    int b = bg >> 7, g = bg & 127;
    int x0 = blockIdx.x * 16, y0 = blockIdx.y * 16;
    __shared__ float tile[4][18][18];
    int t = threadIdx.x;
    for (int idx = t; idx < 4 * 18 * 18; idx += 256) {
        int c = idx / 324;
        int rem = idx - c * 324;
        int r = rem / 18, col = rem - r * 18;
        int ch = (b << 9) + (g << 2) + c;        // b*512 + g*4 + c
        int gh = refl(y0 + r - 1), gw = refl(x0 + col - 1);
        float m = mean[ch], rs = rstd[ch];
        tile[c][r][col] = (x[((size_t)ch << 14) + (gh << 7) + gw] - m) * rs;
    }
    __syncthreads();
    int lx = t & 15, ly = t >> 4;
    const float* w = we + (size_t)bg * 36;
    float acc = bias[bg];
#pragma unroll
    for (int c = 0; c < 4; ++c)
#pragma unroll
        for (int kh = 0; kh < 3; ++kh)
#pragma unroll
            for (int kw = 0; kw < 3; ++kw)
                acc += w[c * 9 + kh * 3 + kw] * tile[c][ly + kh][lx + kw];
    ys[((size_t)bg << 14) + ((size_t)(y0 + ly) << 7) + (x0 + lx)] = acc;
}

// ---------------- Kernel D: final dense 3x3 conv (512 -> 512) ------------
// Tile: 32x32 spatial x 16 out-channels per block; 256 threads;
// each thread: 4 rows x 1 col x 16 co accumulators.
#define CI_T 8
__global__ __launch_bounds__(256) void finalconv_kernel(
        const float* __restrict__ ys, const float* __restrict__ cw,
        const float* __restrict__ cb, float* __restrict__ out) {
    __shared__ float in_t[CI_T][34][34];     // 37 KB
    __shared__ float w_t[16][CI_T][9];       // 4.6 KB
    int t = threadIdx.x;
    int col = t & 31;
    int rb = t >> 5;                          // 0..7
    int x0 = blockIdx.x * 32, y0 = blockIdx.y * 32;
    int co0 = blockIdx.z * 16;

    float acc[4][16];
#pragma unroll
    for (int r = 0; r < 4; ++r)
#pragma unroll
        for (int co = 0; co < 16; ++co) acc[r][co] = 0.f;

    for (int ci0 = 0; ci0 < 512; ci0 += CI_T) {
        __syncthreads();
        // stage input patch (34x34 per ci, reflect-padded)
        for (int idx = t; idx < CI_T * 34 * 34; idx += 256) {
            int ci = idx / 1156;
            int rem = idx - ci * 1156;
            int r = rem / 34, c = rem - r * 34;
            int gh = refl(y0 + r - 1), gw = refl(x0 + c - 1);
            in_t[ci][r][c] = ys[((size_t)(ci0 + ci) << 14) + (gh << 7) + gw];
        }
        // stage weights
        for (int idx = t; idx < 16 * CI_T * 9; idx += 256) {
            int co = idx / (CI_T * 9);
            int rem = idx - co * (CI_T * 9);
            int ci = rem / 9, k = rem - ci * 9;
            w_t[co][ci][k] = cw[((size_t)(co0 + co) * 512 + ci0 + ci) * 9 + k];
        }
        __syncthreads();
#pragma unroll
        for (int ci = 0; ci < CI_T; ++ci) {
            float in_r[6][3];
#pragma unroll
            for (int rr = 0; rr < 6; ++rr)
#pragma unroll
                for (int cc = 0; cc < 3; ++cc)
                    in_r[rr][cc] = in_t[ci][rb * 4 + rr][col + cc];
#pragma unroll
            for (int co = 0; co < 16; ++co) {
#pragma unroll
                for (int kh = 0; kh < 3; ++kh)
#pragma unroll
                    for (int kw = 0; kw < 3; ++kw) {
                        float w = w_t[co][ci][kh * 3 + kw];
#pragma unroll
                        for (int r = 0; r < 4; ++r)
                            acc[r][co] += w * in_r[r + kh][kw];
                    }
            }
        }
    }
#pragma unroll
    for (int co = 0; co < 16; ++co) {
        float b = cb[co0 + co];
#pragma unroll
        for (int r = 0; r < 4; ++r) {
            int oy = y0 + rb * 4 + r;
            out[((size_t)(co0 + co) << 14) + ((size_t)oy << 7) + (x0 + col)] =
                acc[r][co] + b;
        }
    }
}

extern "C" void kernel_launch(void* const* d_in, const int* in_sizes, int n_in,
                              void* d_out, int out_size, void* d_ws, size_t ws_size,
                              hipStream_t stream) {
    const float* x    = (const float*)d_in[0];  // [4,512,128,128]
    const float* wsp  = (const float*)d_in[1];  // [4,512,4,3,3]
    const float* wpw  = (const float*)d_in[2];  // [4,128,4,1,1]
    const float* bias = (const float*)d_in[3];  // [4,128]
    const float* cw   = (const float*)d_in[4];  // [512,512,3,3]
    const float* cb   = (const float*)d_in[5];  // [512]
    float* out = (float*)d_out;                 // [512,128,128]

    char* ws = (char*)d_ws;
    float* ys   = (float*)ws;                          // 33,554,432 B
    float* mean = (float*)(ws + 33554432);             // 8 KB
    float* rstd = (float*)(ws + 33554432 + 8192);      // 8 KB
    float* we   = (float*)(ws + 33554432 + 16384);     // 72 KB

    stats_kernel<<<NBC, 256, 0, stream>>>(x, mean, rstd);
    weff_kernel<<<(4 * 128 * 4 * 9 + 255) / 256, 256, 0, stream>>>(wsp, wpw, we);
    midconv_kernel<<<dim3(8, 8, 512), 256, 0, stream>>>(x, mean, rstd, we, bias, ys);
    finalconv_kernel<<<dim3(4, 4, 32), 256, 0, stream>>>(ys, cw, cb, out);
}

// Round 2
// 375.720 us; speedup vs baseline: 8.4558x; 8.4558x over previous
//
#include <hip/hip_runtime.h>
#include <hip/hip_bf16.h>

// AdaConv2d: instance-norm -> per-sample grouped 3x3 (+fused pointwise) ->
// final dense 512->512 3x3 conv as bf16 MFMA implicit GEMM.
// B=4, C=512, H=W=128. Final conv: M=co(512), N=pix(16384), K=ci(512)x9taps.

typedef unsigned short u16;
typedef __attribute__((ext_vector_type(8))) short bf16x8;
typedef __attribute__((ext_vector_type(4))) float f32x4;

#define HW 16384
#define NBC 2048

__device__ __forceinline__ int refl(int i) {
    return i < 0 ? -i : (i > 127 ? 254 - i : i);
}

__device__ __forceinline__ u16 f2bf(float f) {
    union { float f; unsigned u; } x; x.f = f;
    unsigned r = x.u + 0x7fffu + ((x.u >> 16) & 1u);
    return (u16)(r >> 16);
}

// ---------------- Kernel A: per-(b,c) mean / rstd -------------------------
__global__ __launch_bounds__(256) void stats_kernel(
        const float* __restrict__ x, float* __restrict__ mean,
        float* __restrict__ rstd) {
    int bc = blockIdx.x;
    const float4* p4 = (const float4*)(x + (size_t)bc * HW);
    float s = 0.f, ss = 0.f;
    for (int i = threadIdx.x; i < HW / 4; i += 256) {
        float4 v = p4[i];
        s  += v.x + v.y + v.z + v.w;
        ss += v.x * v.x + v.y * v.y + v.z * v.z + v.w * v.w;
    }
    for (int o = 32; o >= 1; o >>= 1) {
        s  += __shfl_down(s, o);
        ss += __shfl_down(ss, o);
    }
    __shared__ float sm[4], sm2[4];
    int wid = threadIdx.x >> 6, lane = threadIdx.x & 63;
    if (lane == 0) { sm[wid] = s; sm2[wid] = ss; }
    __syncthreads();
    if (threadIdx.x == 0) {
        float S = sm[0] + sm[1] + sm[2] + sm[3];
        float SS = sm2[0] + sm2[1] + sm2[2] + sm2[3];
        float m = S * (1.f / HW);
        float var = SS * (1.f / HW) - m * m;
        mean[bc] = m;
        rstd[bc] = rsqrtf(var + 1e-5f);
    }
}

// ---------------- Kernel B: effective grouped weights ---------------------
__global__ __launch_bounds__(256) void weff_kernel(
        const float* __restrict__ wsp, const float* __restrict__ wpw,
        float* __restrict__ we) {
    int idx = blockIdx.x * 256 + threadIdx.x;
    if (idx >= 4 * 128 * 4 * 9) return;
    int k = idx % 9;
    int c = (idx / 9) & 3;
    int g = (idx / 36) & 127;
    int b = idx / 4608;
    float acc = 0.f;
#pragma unroll
    for (int m = 0; m < 4; ++m) {
        acc += wpw[(b * 128 + g) * 4 + m] *
               wsp[(((size_t)b * 512 + g * 4 + m) * 4 + c) * 9 + k];
    }
    we[idx] = acc;
}

// ---------------- Kernel C: normalized grouped 3x3 conv ------------------
__global__ __launch_bounds__(256) void midconv_kernel(
        const float* __restrict__ x, const float* __restrict__ mean,
        const float* __restrict__ rstd, const float* __restrict__ we,
        const float* __restrict__ bias, float* __restrict__ ys) {
    int bg = blockIdx.z;
    int b = bg >> 7, g = bg & 127;
    int x0 = blockIdx.x * 16, y0 = blockIdx.y * 16;
    __shared__ float tile[4][18][18];
    int t = threadIdx.x;
    for (int idx = t; idx < 4 * 18 * 18; idx += 256) {
        int c = idx / 324;
        int rem = idx - c * 324;
        int r = rem / 18, col = rem - r * 18;
        int ch = (b << 9) + (g << 2) + c;
        int gh = refl(y0 + r - 1), gw = refl(x0 + col - 1);
        float m = mean[ch], rs = rstd[ch];
        tile[c][r][col] = (x[((size_t)ch << 14) + (gh << 7) + gw] - m) * rs;
    }
    __syncthreads();
    int lx = t & 15, ly = t >> 4;
    const float* w = we + (size_t)bg * 36;
    float acc = bias[bg];
#pragma unroll
    for (int c = 0; c < 4; ++c)
#pragma unroll
        for (int kh = 0; kh < 3; ++kh)
#pragma unroll
            for (int kw = 0; kw < 3; ++kw)
                acc += w[c * 9 + kh * 3 + kw] * tile[c][ly + kh][lx + kw];
    ys[((size_t)bg << 14) + ((size_t)(y0 + ly) << 7) + (x0 + lx)] = acc;
}

// ---------------- Kernel T: transpose ys[ci][pix] f32 -> ysT[pix][ci] bf16
__global__ __launch_bounds__(256) void transpose_ys(
        const float* __restrict__ ys, u16* __restrict__ ysT) {
    __shared__ u16 tile[64][72];
    int t = threadIdx.x;
    int pix0 = blockIdx.x * 64, ci0 = blockIdx.y * 64;
    for (int i = t; i < 64 * 16; i += 256) {
        int ci = i >> 4, px = (i & 15) * 4;
        float4 v = *(const float4*)&ys[(size_t)(ci0 + ci) * HW + pix0 + px];
        tile[ci][px + 0] = f2bf(v.x);
        tile[ci][px + 1] = f2bf(v.y);
        tile[ci][px + 2] = f2bf(v.z);
        tile[ci][px + 3] = f2bf(v.w);
    }
    __syncthreads();
    for (int i = t; i < 512; i += 256) {
        int px = i >> 3, c8 = i & 7;
        bf16x8 v;
#pragma unroll
        for (int j = 0; j < 8; ++j) v[j] = (short)tile[c8 * 8 + j][px];
        *(bf16x8*)&ysT[(size_t)(pix0 + px) * 512 + ci0 + c8 * 8] = v;
    }
}

// ---------------- Kernel W: pack conv_w -> wT[tap][co][ci] bf16 -----------
__global__ __launch_bounds__(256) void wpack_kernel(
        const float* __restrict__ cw, u16* __restrict__ wT) {
    int idx = blockIdx.x * 256 + threadIdx.x;
    if (idx >= 9 * 512 * 512) return;
    int ci = idx & 511;
    int co = (idx >> 9) & 511;
    int tap = idx >> 18;
    wT[idx] = f2bf(cw[(size_t)co * 4608 + ci * 9 + tap]);
}

// ---------------- Kernel D: final conv via MFMA ---------------------------
// Block: 64 co x 256 pix (2 image rows), 256 thr (4 waves), wave = 64x64.
// LDS: ysT halo tile [4*130 rows pad 528][32 ci] + wT tile [9*64][32 ci].
__device__ __forceinline__ void load_lds16(const u16* g, u16* l) {
    __builtin_amdgcn_global_load_lds(
        (const __attribute__((address_space(1))) unsigned int*)g,
        (__attribute__((address_space(3))) unsigned int*)l, 16, 0, 0);
}

__global__ __launch_bounds__(256, 2) void finalconv_mfma(
        const u16* __restrict__ ysT, const u16* __restrict__ wT,
        const float* __restrict__ cb, float* __restrict__ out) {
    __shared__ u16 lds_ys[528 * 32];   // [p][ci], chunk-swizzled, 33 KB
    __shared__ u16 lds_wt[576 * 32];   // [tap*64+co][ci], swizzled, 36.9 KB
    int t = threadIdx.x;
    int w = t >> 6, l = t & 63;
    int m = l & 15, q = l >> 4;
    int co0 = blockIdx.x * 64;
    int y0 = blockIdx.y * 2;
    int tr = w >> 1, xw = (w & 1) * 64;

    f32x4 acc[4][4];
#pragma unroll
    for (int i = 0; i < 4; ++i)
#pragma unroll
        for (int j = 0; j < 4; ++j) acc[i][j] = (f32x4){0.f, 0.f, 0.f, 0.f};

    for (int ci0 = 0; ci0 < 512; ci0 += 32) {
        __syncthreads();
        // ---- stage via global_load_lds (linear LDS dest, pre-swizzled src)
        for (int i = w; i < 69; i += 4) {
            if (i < 33) {                       // ysT tile: 528 rows x 64B
                int s = i * 64 + l;
                int p = s >> 2, c = s & 3;
                int pc = p > 519 ? 519 : p;
                int hr = (pc * 1009) >> 17;     // pc / 130
                int hc = pc - hr * 130;
                int gy = refl(y0 + hr - 1), gx = refl(hc - 1);
                int ci8 = c ^ ((p >> 1) & 3);
                const u16* src = ysT + (size_t)((gy << 7) + gx) * 512 + ci0 + ci8 * 8;
                load_lds16(src, &lds_ys[i * 512]);
            } else {                            // wT tile: 576 rows x 64B
                int k = i - 33;
                int s = k * 64 + l;
                int row = s >> 2, c = s & 3;
                int tap = row >> 6, co_l = row & 63;
                int ci8 = c ^ ((co_l >> 1) & 3);
                const u16* src = wT + (size_t)((tap << 9) + co0 + co_l) * 512 + ci0 + ci8 * 8;
                load_lds16(src, &lds_wt[k * 512]);
            }
        }
        __syncthreads();
        // ---- compute: 9 taps x 4x4 fragments
#pragma unroll
        for (int tap = 0; tap < 9; ++tap) {
            const int dyi = tap / 3, dxi = tap % 3;
            bf16x8 a[4], b[4];
#pragma unroll
            for (int i = 0; i < 4; ++i) {
                int co_l = i * 16 + m;
                int ch = q ^ ((co_l >> 1) & 3);
                a[i] = *(const bf16x8*)&lds_wt[(tap * 64 + co_l) * 32 + ch * 8];
            }
#pragma unroll
            for (int j = 0; j < 4; ++j) {
                int xx = xw + j * 16 + m;
                int p = (tr + dyi) * 130 + xx + dxi;
                int ch = q ^ ((p >> 1) & 3);
                b[j] = *(const bf16x8*)&lds_ys[p * 32 + ch * 8];
            }
#pragma unroll
            for (int i = 0; i < 4; ++i)
#pragma unroll
                for (int j = 0; j < 4; ++j)
                    acc[i][j] = __builtin_amdgcn_mfma_f32_16x16x32_bf16(
                        a[i], b[j], acc[i][j], 0, 0, 0);
        }
    }
    // ---- epilogue: D row = co (q*4+r), col = pix (m)
    int gyo = y0 + tr;
#pragma unroll
    for (int i = 0; i < 4; ++i) {
        int cob = co0 + i * 16 + q * 4;
#pragma unroll
        for (int j = 0; j < 4; ++j) {
            int xx = xw + j * 16 + m;
            float* o = out + (size_t)cob * HW + (gyo << 7) + xx;
#pragma unroll
            for (int r = 0; r < 4; ++r)
                o[(size_t)r * HW] = acc[i][j][r] + cb[cob + r];
        }
    }
}

extern "C" void kernel_launch(void* const* d_in, const int* in_sizes, int n_in,
                              void* d_out, int out_size, void* d_ws, size_t ws_size,
                              hipStream_t stream) {
    const float* x    = (const float*)d_in[0];
    const float* wsp  = (const float*)d_in[1];
    const float* wpw  = (const float*)d_in[2];
    const float* bias = (const float*)d_in[3];
    const float* cw   = (const float*)d_in[4];
    const float* cb   = (const float*)d_in[5];
    float* out = (float*)d_out;

    char* ws = (char*)d_ws;
    float* ys   = (float*)ws;                               // 33,554,432 B
    u16*   ysT  = (u16*)(ws + 33554432);                    // 16,777,216 B
    u16*   wT   = (u16*)(ws + 33554432 + 16777216);         //  4,718,592 B
    float* mean = (float*)(ws + 55050240);                  //      8,192 B
    float* rstd = (float*)(ws + 55058432);                  //      8,192 B
    float* we   = (float*)(ws + 55066624);                  //     73,728 B

    stats_kernel<<<NBC, 256, 0, stream>>>(x, mean, rstd);
    weff_kernel<<<(4 * 128 * 4 * 9 + 255) / 256, 256, 0, stream>>>(wsp, wpw, we);
    wpack_kernel<<<(9 * 512 * 512 + 255) / 256, 256, 0, stream>>>(cw, wT);
    midconv_kernel<<<dim3(8, 8, 512), 256, 0, stream>>>(x, mean, rstd, we, bias, ys);
    transpose_ys<<<dim3(256, 8), 256, 0, stream>>>(ys, ysT);
    finalconv_mfma<<<dim3(8, 64), 256, 0, stream>>>(ysT, wT, cb, out);
}

// Round 4
// 372.755 us; speedup vs baseline: 8.5230x; 1.0080x over previous
//
#include <hip/hip_runtime.h>
#include <hip/hip_bf16.h>

// AdaConv2d: instance-norm (folded into weights) -> per-sample grouped 3x3
// (+fused pointwise) writing ysT[pix][ci] bf16 directly -> final dense
// 512->512 3x3 conv as bf16 MFMA implicit GEMM.
// B=4, C=512, H=W=128. Final conv: M=co(512), N=pix(16384), K=ci(512)x9taps.

typedef unsigned short u16;
typedef __attribute__((ext_vector_type(8))) short bf16x8;
typedef __attribute__((ext_vector_type(4))) float f32x4;

#define HW 16384
#define NBC 2048

__device__ __forceinline__ int refl(int i) {
    return i < 0 ? -i : (i > 127 ? 254 - i : i);
}

__device__ __forceinline__ u16 f2bf(float f) {
    union { float f; unsigned u; } x; x.f = f;
    unsigned r = x.u + 0x7fffu + ((x.u >> 16) & 1u);
    return (u16)(r >> 16);
}

__device__ __forceinline__ void load_lds16(const u16* g, u16* l) {
    __builtin_amdgcn_global_load_lds(
        (const __attribute__((address_space(1))) unsigned int*)g,
        (__attribute__((address_space(3))) unsigned int*)l, 16, 0, 0);
}

__device__ __forceinline__ void load_lds4(const float* g, float* l) {
    __builtin_amdgcn_global_load_lds(
        (const __attribute__((address_space(1))) unsigned int*)g,
        (__attribute__((address_space(3))) unsigned int*)l, 4, 0, 0);
}

// ---------------- Kernel A: per-(b,c) mean / rstd -------------------------
__global__ __launch_bounds__(256) void stats_kernel(
        const float* __restrict__ x, float* __restrict__ mean,
        float* __restrict__ rstd) {
    int bc = blockIdx.x;
    const float4* p4 = (const float4*)(x + (size_t)bc * HW);
    float s = 0.f, ss = 0.f;
    for (int i = threadIdx.x; i < HW / 4; i += 256) {
        float4 v = p4[i];
        s  += v.x + v.y + v.z + v.w;
        ss += v.x * v.x + v.y * v.y + v.z * v.z + v.w * v.w;
    }
    for (int o = 32; o >= 1; o >>= 1) {
        s  += __shfl_down(s, o);
        ss += __shfl_down(ss, o);
    }
    __shared__ float sm[4], sm2[4];
    int wid = threadIdx.x >> 6, lane = threadIdx.x & 63;
    if (lane == 0) { sm[wid] = s; sm2[wid] = ss; }
    __syncthreads();
    if (threadIdx.x == 0) {
        float S = sm[0] + sm[1] + sm[2] + sm[3];
        float SS = sm2[0] + sm2[1] + sm2[2] + sm2[3];
        float m = S * (1.f / HW);
        float var = SS * (1.f / HW) - m * m;
        mean[bc] = m;
        rstd[bc] = rsqrtf(var + 1e-5f);
    }
}

// ---------------- Kernel B: effective grouped weights ---------------------
__global__ __launch_bounds__(256) void weff_kernel(
        const float* __restrict__ wsp, const float* __restrict__ wpw,
        float* __restrict__ we) {
    int idx = blockIdx.x * 256 + threadIdx.x;
    if (idx >= 4 * 128 * 4 * 9) return;
    int k = idx % 9;
    int c = (idx / 9) & 3;
    int g = (idx / 36) & 127;
    int b = idx / 4608;
    float acc = 0.f;
#pragma unroll
    for (int m = 0; m < 4; ++m) {
        acc += wpw[(b * 128 + g) * 4 + m] *
               wsp[(((size_t)b * 512 + g * 4 + m) * 4 + c) * 9 + k];
    }
    we[idx] = acc;
}

// ---------------- Kernel W: pack conv_w -> wT[tap][co][ci] bf16 -----------
// Block per co: coalesced 18.4 KB read, LDS transpose, 1 KB writes per tap.
__global__ __launch_bounds__(256) void wpack_kernel(
        const float* __restrict__ cw, u16* __restrict__ wT) {
    __shared__ float s[512 * 10];        // [ci][tap pad 10]
    int t = threadIdx.x, co = blockIdx.x;
    const float* src = cw + (size_t)co * 4608;
    for (int i = t; i < 4608; i += 256) {
        int ci = i / 9, tap = i - ci * 9;
        s[ci * 10 + tap] = src[i];
    }
    __syncthreads();
#pragma unroll
    for (int tap = 0; tap < 9; ++tap) {
        unsigned lo = (unsigned)f2bf(s[(2 * t) * 10 + tap]);
        unsigned hi = (unsigned)f2bf(s[(2 * t + 1) * 10 + tap]);
        ((unsigned*)&wT[((size_t)(tap << 9) + co) * 512])[t] = lo | (hi << 16);
    }
}

// ---------------- Kernel C: fused norm+grouped conv -> ysT bf16 -----------
// Block = (batch, 16x16 spatial tile), 512 threads. Loop over 32 group-quads.
// Norm folded into weights: tile holds RAW x (global_load_lds, lane-linear).
// Output staged in outb[256 pix][64 g half] bf16, flushed twice, coalesced.
__global__ __launch_bounds__(512) void midconv_fused(
        const float* __restrict__ x, const float* __restrict__ mean,
        const float* __restrict__ rstd, const float* __restrict__ we,
        const float* __restrict__ bias, u16* __restrict__ ysT) {
    __shared__ float tile[16 * 324];      // 16 ch x 18x18, LINEAR (20.7 KB)
    __shared__ u16 outb[256 * 72];        // [pix][64 g + pad] (36.9 KB)
    __shared__ float s_mean[512], s_rstd[512];
    __shared__ float s_w[144];            // 4 groups x 36, rstd-folded
    __shared__ float s_bias[4];
    int t = threadIdx.x;
    int b = blockIdx.y;
    int x0 = (blockIdx.x & 7) << 4, y0 = (blockIdx.x >> 3) << 4;

    // preload per-channel stats for this batch
    s_mean[t] = mean[(b << 9) + t];
    s_rstd[t] = rstd[(b << 9) + t];

    // precompute staging slots (lane-linear LDS dest => idx itself)
    int soff[11];
#pragma unroll
    for (int s = 0; s < 11; ++s) {
        int idx = t + (s << 9);
        int id2 = idx < 5184 ? idx : 0;
        int c8 = id2 / 324;
        int rm = id2 - c8 * 324;
        int r = rm / 18, col = rm - r * 18;
        soff[s] = (c8 << 14) + (refl(y0 + r - 1) << 7) + refl(x0 + col - 1);
    }

    int gq = t >> 7;              // 0..3: group within quad
    int rem = t & 127;
    int py = rem >> 3;            // 0..15
    int px0 = (rem & 7) << 1;     // 0,2,..,14
    const float* wq = &s_w[gq * 36];

    for (int q_i = 0; q_i < 32; ++q_i) {
        __syncthreads();
        // flush first 64-group half before its outb columns get reused
        if (q_i == 16) {
            for (int i = t; i < 2048; i += 512) {
                int pix = i >> 3, seg = i & 7;
                bf16x8 v = *(const bf16x8*)&outb[pix * 72 + (seg << 3)];
                int ppy = pix >> 4, ppx = pix & 15;
                size_t gp = (size_t)(((y0 + ppy) << 7) + x0 + ppx);
                *(bf16x8*)&ysT[gp * 512 + (b << 7) + (seg << 3)] = v;
            }
        }
        // ---- stage raw x tile via global_load_lds (width 4, lane-linear)
        const float* xq = x + ((size_t)((b << 9) + (q_i << 4)) << 14);
#pragma unroll
        for (int s = 0; s < 10; ++s)
            load_lds4(xq + soff[s], &tile[t + (s << 9)]);
        if (t < 64) load_lds4(xq + soff[10], &tile[t + 5120]);
        // ---- fold rstd into weights; fold mean into bias
        if (t < 144) {
            int g_rel = t / 36, rr = t - g_rel * 36;
            int c = rr / 9;
            int group = (q_i << 2) + g_rel;
            s_w[t] = we[((b << 7) + group) * 36 + rr] *
                     s_rstd[(group << 2) + c];
        }
        if (t < 4) {
            int group = (q_i << 2) + t;
            float bsum = bias[(b << 7) + group];
            const float* wrow = we + ((b << 7) + group) * 36;
#pragma unroll
            for (int j = 0; j < 36; ++j) {
                int ch_l = (group << 2) + (j / 9);
                bsum -= wrow[j] * s_rstd[ch_l] * s_mean[ch_l];
            }
            s_bias[t] = bsum;
        }
        __syncthreads();   // drains vmcnt: tile + s_w ready
        // ---- compute: 2 horizontal outputs per thread
        float a0 = s_bias[gq], a1 = a0;
#pragma unroll
        for (int c = 0; c < 4; ++c) {
            const float* tp = &tile[(gq * 4 + c) * 324];
#pragma unroll
            for (int kh = 0; kh < 3; ++kh) {
                float2 u = *(const float2*)&tp[(py + kh) * 18 + px0];
                float2 v = *(const float2*)&tp[(py + kh) * 18 + px0 + 2];
                float w0 = wq[c * 9 + kh * 3 + 0];
                float w1 = wq[c * 9 + kh * 3 + 1];
                float w2 = wq[c * 9 + kh * 3 + 2];
                a0 += w0 * u.x + w1 * u.y + w2 * v.x;
                a1 += w0 * u.y + w1 * v.x + w2 * v.y;
            }
        }
        int col = ((q_i << 2) + gq) & 63;
        int pix = (py << 4) + px0;
        outb[pix * 72 + col] = f2bf(a0);
        outb[(pix + 1) * 72 + col] = f2bf(a1);
    }
    __syncthreads();
    // flush second half (groups 64..127)
    for (int i = t; i < 2048; i += 512) {
        int pix = i >> 3, seg = i & 7;
        bf16x8 v = *(const bf16x8*)&outb[pix * 72 + (seg << 3)];
        int ppy = pix >> 4, ppx = pix & 15;
        size_t gp = (size_t)(((y0 + ppy) << 7) + x0 + ppx);
        *(bf16x8*)&ysT[gp * 512 + (b << 7) + 64 + (seg << 3)] = v;
    }
}

// ---------------- Kernel D: final conv via MFMA ---------------------------
// Block: 64 co x 256 pix (2 image rows), 256 thr (4 waves), wave = 64x64.
// LDS: ysT halo tile [4*130 rows pad 528][32 ci] + wT tile [9*64][32 ci].
// 1D grid of 512 with bijective XCD swizzle: XCD k owns y-blocks 8k..8k+7.
__global__ __launch_bounds__(256, 2) void finalconv_mfma(
        const u16* __restrict__ ysT, const u16* __restrict__ wT,
        const float* __restrict__ cb, float* __restrict__ out) {
    __shared__ u16 lds_ys[528 * 32];   // chunk-swizzled, 33 KB
    __shared__ u16 lds_wt[576 * 32];   // swizzled, 36.9 KB
    int t = threadIdx.x;
    int w = t >> 6, l = t & 63;
    int m = l & 15, q = l >> 4;
    int bid = blockIdx.x;
    int swz = ((bid & 7) << 6) + (bid >> 3);
    int co0 = (swz & 7) << 6;
    int y0 = (swz >> 3) << 1;
    int tr = w >> 1, xw = (w & 1) * 64;

    f32x4 acc[4][4];
#pragma unroll
    for (int i = 0; i < 4; ++i)
#pragma unroll
        for (int j = 0; j < 4; ++j) acc[i][j] = (f32x4){0.f, 0.f, 0.f, 0.f};

    for (int ci0 = 0; ci0 < 512; ci0 += 32) {
        __syncthreads();
        for (int i = w; i < 69; i += 4) {
            if (i < 33) {                       // ysT tile: 528 rows x 64B
                int s = i * 64 + l;
                int p = s >> 2, c = s & 3;
                int pc = p > 519 ? 519 : p;
                int hr = (pc * 1009) >> 17;     // pc / 130
                int hc = pc - hr * 130;
                int gy = refl(y0 + hr - 1), gx = refl(hc - 1);
                int ci8 = c ^ ((p >> 1) & 3);
                const u16* src = ysT + (size_t)((gy << 7) + gx) * 512 + ci0 + ci8 * 8;
                load_lds16(src, &lds_ys[i * 512]);
            } else {                            // wT tile: 576 rows x 64B
                int k = i - 33;
                int s = k * 64 + l;
                int row = s >> 2, c = s & 3;
                int tap = row >> 6, co_l = row & 63;
                int ci8 = c ^ ((co_l >> 1) & 3);
                const u16* src = wT + (size_t)((tap << 9) + co0 + co_l) * 512 + ci0 + ci8 * 8;
                load_lds16(src, &lds_wt[k * 512]);
            }
        }
        __syncthreads();
#pragma unroll
        for (int tap = 0; tap < 9; ++tap) {
            const int dyi = tap / 3, dxi = tap % 3;
            bf16x8 a[4], b[4];
#pragma unroll
            for (int i = 0; i < 4; ++i) {
                int co_l = i * 16 + m;
                int ch = q ^ ((co_l >> 1) & 3);
                a[i] = *(const bf16x8*)&lds_wt[(tap * 64 + co_l) * 32 + ch * 8];
            }
#pragma unroll
            for (int j = 0; j < 4; ++j) {
                int xx = xw + j * 16 + m;
                int p = (tr + dyi) * 130 + xx + dxi;
                int ch = q ^ ((p >> 1) & 3);
                b[j] = *(const bf16x8*)&lds_ys[p * 32 + ch * 8];
            }
#pragma unroll
            for (int i = 0; i < 4; ++i)
#pragma unroll
                for (int j = 0; j < 4; ++j)
                    acc[i][j] = __builtin_amdgcn_mfma_f32_16x16x32_bf16(
                        a[i], b[j], acc[i][j], 0, 0, 0);
        }
    }
    int gyo = y0 + tr;
#pragma unroll
    for (int i = 0; i < 4; ++i) {
        int cob = co0 + i * 16 + q * 4;
#pragma unroll
        for (int j = 0; j < 4; ++j) {
            int xx = xw + j * 16 + m;
            float* o = out + (size_t)cob * HW + (gyo << 7) + xx;
#pragma unroll
            for (int r = 0; r < 4; ++r)
                o[(size_t)r * HW] = acc[i][j][r] + cb[cob + r];
        }
    }
}

extern "C" void kernel_launch(void* const* d_in, const int* in_sizes, int n_in,
                              void* d_out, int out_size, void* d_ws, size_t ws_size,
                              hipStream_t stream) {
    const float* x    = (const float*)d_in[0];
    const float* wsp  = (const float*)d_in[1];
    const float* wpw  = (const float*)d_in[2];
    const float* bias = (const float*)d_in[3];
    const float* cw   = (const float*)d_in[4];
    const float* cb   = (const float*)d_in[5];
    float* out = (float*)d_out;

    char* ws = (char*)d_ws;
    u16*   ysT  = (u16*)ws;                        // 16,777,216 B
    u16*   wT   = (u16*)(ws + 16777216);           //  4,718,592 B
    float* mean = (float*)(ws + 21495808);         //      8,192 B
    float* rstd = (float*)(ws + 21504000);         //      8,192 B
    float* we   = (float*)(ws + 21512192);         //     73,728 B

    stats_kernel<<<NBC, 256, 0, stream>>>(x, mean, rstd);
    weff_kernel<<<(4 * 128 * 4 * 9 + 255) / 256, 256, 0, stream>>>(wsp, wpw, we);
    wpack_kernel<<<512, 256, 0, stream>>>(cw, wT);
    midconv_fused<<<dim3(64, 4), 512, 0, stream>>>(x, mean, rstd, we, bias, ysT);
    finalconv_mfma<<<512, 256, 0, stream>>>(ysT, wT, cb, out);
}

// Round 6
// 366.364 us; speedup vs baseline: 8.6717x; 1.0174x over previous
//
#include <hip/hip_runtime.h>
#include <hip/hip_bf16.h>

// AdaConv2d: instance-norm (folded into weights) -> per-sample grouped 3x3
// (+fused pointwise) writing ysT[pix][ci] bf16 directly -> final dense
// 512->512 3x3 conv as bf16 MFMA implicit GEMM.
// B=4, C=512, H=W=128. Final conv: M=co(512), N=pix(16384), K=ci(512)x9taps.

typedef unsigned short u16;
typedef __attribute__((ext_vector_type(8))) short bf16x8;
typedef __attribute__((ext_vector_type(4))) float f32x4;

#define HW 16384
#define NBC 2048

__device__ __forceinline__ int refl(int i) {
    return i < 0 ? -i : (i > 127 ? 254 - i : i);
}

__device__ __forceinline__ u16 f2bf(float f) {
    union { float f; unsigned u; } x; x.f = f;
    unsigned r = x.u + 0x7fffu + ((x.u >> 16) & 1u);
    return (u16)(r >> 16);
}

__device__ __forceinline__ void load_lds16(const u16* g, u16* l) {
    __builtin_amdgcn_global_load_lds(
        (const __attribute__((address_space(1))) unsigned int*)g,
        (__attribute__((address_space(3))) unsigned int*)l, 16, 0, 0);
}

__device__ __forceinline__ void load_lds16f(const float* g, float* l) {
    __builtin_amdgcn_global_load_lds(
        (const __attribute__((address_space(1))) unsigned int*)g,
        (__attribute__((address_space(3))) unsigned int*)l, 16, 0, 0);
}

__device__ __forceinline__ void load_lds4(const float* g, float* l) {
    __builtin_amdgcn_global_load_lds(
        (const __attribute__((address_space(1))) unsigned int*)g,
        (__attribute__((address_space(3))) unsigned int*)l, 4, 0, 0);
}

// ---------------- Kernel A: per-(b,c) mean / rstd -------------------------
__global__ __launch_bounds__(256) void stats_kernel(
        const float* __restrict__ x, float* __restrict__ mean,
        float* __restrict__ rstd) {
    int bc = blockIdx.x;
    const float4* p4 = (const float4*)(x + (size_t)bc * HW);
    float s = 0.f, ss = 0.f;
    for (int i = threadIdx.x; i < HW / 4; i += 256) {
        float4 v = p4[i];
        s  += v.x + v.y + v.z + v.w;
        ss += v.x * v.x + v.y * v.y + v.z * v.z + v.w * v.w;
    }
    for (int o = 32; o >= 1; o >>= 1) {
        s  += __shfl_down(s, o);
        ss += __shfl_down(ss, o);
    }
    __shared__ float sm[4], sm2[4];
    int wid = threadIdx.x >> 6, lane = threadIdx.x & 63;
    if (lane == 0) { sm[wid] = s; sm2[wid] = ss; }
    __syncthreads();
    if (threadIdx.x == 0) {
        float S = sm[0] + sm[1] + sm[2] + sm[3];
        float SS = sm2[0] + sm2[1] + sm2[2] + sm2[3];
        float m = S * (1.f / HW);
        float var = SS * (1.f / HW) - m * m;
        mean[bc] = m;
        rstd[bc] = rsqrtf(var + 1e-5f);
    }
}

// ---------------- Kernel B: effective grouped weights, rstd-folded --------
// wf[b,g,c,k] = rstd[b,g*4+c] * sum_m wp[b,g,m] * ws[b,g*4+m,c,k]
__global__ __launch_bounds__(256) void weff_kernel(
        const float* __restrict__ wsp, const float* __restrict__ wpw,
        const float* __restrict__ rstd, float* __restrict__ wf) {
    int idx = blockIdx.x * 256 + threadIdx.x;
    if (idx >= 4 * 128 * 4 * 9) return;
    int k = idx % 9;
    int c = (idx / 9) & 3;
    int g = (idx / 36) & 127;
    int b = idx / 4608;
    float acc = 0.f;
#pragma unroll
    for (int m = 0; m < 4; ++m) {
        acc += wpw[(b * 128 + g) * 4 + m] *
               wsp[(((size_t)b * 512 + g * 4 + m) * 4 + c) * 9 + k];
    }
    wf[idx] = acc * rstd[(b << 9) + (g << 2) + c];
}

// ---------------- Kernel B2: folded bias ----------------------------------
// bf[bg] = bias[bg] - sum_j wf[bg*36+j] * mean[4*bg + j/9]
__global__ __launch_bounds__(256) void bias_fold(
        const float* __restrict__ wf, const float* __restrict__ bias,
        const float* __restrict__ mean, float* __restrict__ bf) {
    int bg = blockIdx.x * 256 + threadIdx.x;
    if (bg >= 512) return;
    float s = bias[bg];
    const float* w = wf + bg * 36;
    const float* m = mean + (bg << 2);
#pragma unroll
    for (int j = 0; j < 36; ++j) s -= w[j] * m[j / 9];
    bf[bg] = s;
}

// ---------------- Kernel W: pack conv_w -> wT[tap][co][ci] bf16 -----------
// Block per co. Stride-9 LDS reads (odd -> 2-way, free); coalesced u16 out.
__global__ __launch_bounds__(256) void wpack_kernel(
        const float* __restrict__ cw, u16* __restrict__ wT) {
    __shared__ float s[4608];
    int t = threadIdx.x, co = blockIdx.x;
    const float* src = cw + (size_t)co * 4608;
    for (int i = t; i < 4608; i += 256) s[i] = src[i];
    __syncthreads();
#pragma unroll
    for (int tap = 0; tap < 9; ++tap) {
        u16* dst = &wT[((size_t)(tap << 9) + co) * 512];
        dst[t]       = f2bf(s[t * 9 + tap]);
        dst[t + 256] = f2bf(s[(t + 256) * 9 + tap]);
    }
}

// ---------------- Kernel C: fused norm+grouped conv -> ysT bf16 -----------
// Block = (batch, 8x16 spatial tile), 512 threads, grid 512 (2 blocks/CU).
// Double-buffered width-16 staging: mid[16ch][10r][16cols] (lane-linear) +
// halo cols staged separately. All weights preloaded once (rstd/mean folded).
__global__ __launch_bounds__(512) void midconv_fused(
        const float* __restrict__ x, const float* __restrict__ wf,
        const float* __restrict__ bf, u16* __restrict__ ysT) {
    __shared__ float mid[2][2560];     // [buf][ch*160 + r*16 + j]  20.5 KB
    __shared__ float halo[2][320];     // [buf][side*160 + ch*10 + r] 2.5 KB
    __shared__ u16 outb[128 * 72];     // [pix][64ch + pad]          18.4 KB
    __shared__ float s_w[4608];        // all 128 groups x 36        18.4 KB
    __shared__ float s_b[128];
    int t = threadIdx.x;
    int b = blockIdx.y;
    int x0 = (blockIdx.x & 7) << 4, y0 = (blockIdx.x >> 3) << 3;

    for (int i = t; i < 4608; i += 512) s_w[i] = wf[b * 4608 + i];
    if (t < 128) s_b[t] = bf[(b << 7) + t];

    // precompute per-lane global source offsets (constant over q)
    int smid0, smid1, shalo;
    {
        int ch = t / 40, rem = t - ch * 40;
        int r = rem >> 2, j = rem & 3;
        smid0 = (ch << 14) + (refl(y0 + r - 1) << 7) + x0 + (j << 2);
        int i1 = t + 512 < 640 ? t + 512 : 0;
        ch = i1 / 40; rem = i1 - ch * 40; r = rem >> 2; j = rem & 3;
        smid1 = (ch << 14) + (refl(y0 + r - 1) << 7) + x0 + (j << 2);
        int ih = t < 320 ? t : 0;
        int side = ih >= 160;
        int hh = side ? ih - 160 : ih;
        ch = hh / 10; r = hh - ch * 10;
        int col = side ? refl(x0 + 16) : refl(x0 - 1);
        shalo = (ch << 14) + (refl(y0 + r - 1) << 7) + col;
    }

    int gq = t >> 7;                 // group within quad (0..3)
    int rem = t & 127;
    int py = rem >> 4, px = rem & 15;

    // prologue: stage q=0 into buf 0
    {
        const float* xq = x + ((size_t)(b << 9) << 14);
        load_lds16f(xq + smid0, &mid[0][t * 4]);
        if (t < 128) load_lds16f(xq + smid1, &mid[0][(512 + t) * 4]);
        if (t < 320) load_lds4(xq + shalo, &halo[0][t]);
    }

    for (int q = 0; q < 32; ++q) {
        __syncthreads();             // drains vmcnt: buf[q&1] ready
        if (q == 16) {               // flush groups 0..63 (written <= q15)
            for (int i = t; i < 1024; i += 512) {
                int pix = i >> 3, seg = i & 7;
                bf16x8 v = *(const bf16x8*)&outb[pix * 72 + (seg << 3)];
                int ppy = pix >> 4, ppx = pix & 15;
                size_t gp = (size_t)(((y0 + ppy) << 7) + x0 + ppx);
                *(bf16x8*)&ysT[gp * 512 + (b << 7) + (seg << 3)] = v;
            }
            __syncthreads();
        }
        int cur = q & 1;
        if (q < 31) {                // issue next-tile loads (overlap compute)
            const float* xq = x + ((size_t)((b << 9) + ((q + 1) << 4)) << 14);
            load_lds16f(xq + smid0, &mid[cur ^ 1][t * 4]);
            if (t < 128) load_lds16f(xq + smid1, &mid[cur ^ 1][(512 + t) * 4]);
            if (t < 320) load_lds4(xq + shalo, &halo[cur ^ 1][t]);
        }
        // compute: 1 output pixel per thread for group q*4+gq
        int group = (q << 2) + gq;
        float acc = s_b[group];
        const float* wq = &s_w[group * 36];
#pragma unroll
        for (int c = 0; c < 4; ++c) {
            const float* tp  = &mid[cur][(gq * 4 + c) * 160];
            const float* hlc = &halo[cur][(gq * 4 + c) * 10];
            const float* hrc = &halo[cur][160 + (gq * 4 + c) * 10];
#pragma unroll
            for (int kh = 0; kh < 3; ++kh) {
                int row = py + kh;
                const float* rp = tp + row * 16;
                float m0 = (px == 0)  ? hlc[row] : rp[px - 1];
                float m1 = rp[px];
                float m2 = (px == 15) ? hrc[row] : rp[px + 1];
                acc += wq[c * 9 + kh * 3 + 0] * m0 +
                       wq[c * 9 + kh * 3 + 1] * m1 +
                       wq[c * 9 + kh * 3 + 2] * m2;
            }
        }
        outb[(py * 16 + px) * 72 + (group & 63)] = f2bf(acc);
    }
    __syncthreads();
    // flush groups 64..127
    for (int i = t; i < 1024; i += 512) {
        int pix = i >> 3, seg = i & 7;
        bf16x8 v = *(const bf16x8*)&outb[pix * 72 + (seg << 3)];
        int ppy = pix >> 4, ppx = pix & 15;
        size_t gp = (size_t)(((y0 + ppy) << 7) + x0 + ppx);
        *(bf16x8*)&ysT[gp * 512 + (b << 7) + 64 + (seg << 3)] = v;
    }
}

// ---------------- Kernel D: final conv via MFMA ---------------------------
// Block: 64 co x 256 pix (2 image rows), 256 thr (4 waves), wave = 64x64.
// LDS: ysT halo tile [4*130 rows pad 528][32 ci] + wT tile [9*64][32 ci].
// 1D grid of 512 with bijective XCD swizzle: XCD k owns y-blocks 8k..8k+7.
__global__ __launch_bounds__(256, 2) void finalconv_mfma(
        const u16* __restrict__ ysT, const u16* __restrict__ wT,
        const float* __restrict__ cb, float* __restrict__ out) {
    __shared__ u16 lds_ys[528 * 32];   // chunk-swizzled, 33 KB
    __shared__ u16 lds_wt[576 * 32];   // swizzled, 36.9 KB
    int t = threadIdx.x;
    int w = t >> 6, l = t & 63;
    int m = l & 15, q = l >> 4;
    int bid = blockIdx.x;
    int swz = ((bid & 7) << 6) + (bid >> 3);
    int co0 = (swz & 7) << 6;
    int y0 = (swz >> 3) << 1;
    int tr = w >> 1, xw = (w & 1) * 64;

    f32x4 acc[4][4];
#pragma unroll
    for (int i = 0; i < 4; ++i)
#pragma unroll
        for (int j = 0; j < 4; ++j) acc[i][j] = (f32x4){0.f, 0.f, 0.f, 0.f};

    for (int ci0 = 0; ci0 < 512; ci0 += 32) {
        __syncthreads();
        for (int i = w; i < 69; i += 4) {
            if (i < 33) {                       // ysT tile: 528 rows x 64B
                int s = i * 64 + l;
                int p = s >> 2, c = s & 3;
                int pc = p > 519 ? 519 : p;
                int hr = (pc * 1009) >> 17;     // pc / 130
                int hc = pc - hr * 130;
                int gy = refl(y0 + hr - 1), gx = refl(hc - 1);
                int ci8 = c ^ ((p >> 1) & 3);
                const u16* src = ysT + (size_t)((gy << 7) + gx) * 512 + ci0 + ci8 * 8;
                load_lds16(src, &lds_ys[i * 512]);
            } else {                            // wT tile: 576 rows x 64B
                int k = i - 33;
                int s = k * 64 + l;
                int row = s >> 2, c = s & 3;
                int tap = row >> 6, co_l = row & 63;
                int ci8 = c ^ ((co_l >> 1) & 3);
                const u16* src = wT + (size_t)((tap << 9) + co0 + co_l) * 512 + ci0 + ci8 * 8;
                load_lds16(src, &lds_wt[k * 512]);
            }
        }
        __syncthreads();
#pragma unroll
        for (int tap = 0; tap < 9; ++tap) {
            const int dyi = tap / 3, dxi = tap % 3;
            bf16x8 a[4], b[4];
#pragma unroll
            for (int i = 0; i < 4; ++i) {
                int co_l = i * 16 + m;
                int ch = q ^ ((co_l >> 1) & 3);
                a[i] = *(const bf16x8*)&lds_wt[(tap * 64 + co_l) * 32 + ch * 8];
            }
#pragma unroll
            for (int j = 0; j < 4; ++j) {
                int xx = xw + j * 16 + m;
                int p = (tr + dyi) * 130 + xx + dxi;
                int ch = q ^ ((p >> 1) & 3);
                b[j] = *(const bf16x8*)&lds_ys[p * 32 + ch * 8];
            }
#pragma unroll
            for (int i = 0; i < 4; ++i)
#pragma unroll
                for (int j = 0; j < 4; ++j)
                    acc[i][j] = __builtin_amdgcn_mfma_f32_16x16x32_bf16(
                        a[i], b[j], acc[i][j], 0, 0, 0);
        }
    }
    int gyo = y0 + tr;
#pragma unroll
    for (int i = 0; i < 4; ++i) {
        int cob = co0 + i * 16 + q * 4;
#pragma unroll
        for (int j = 0; j < 4; ++j) {
            int xx = xw + j * 16 + m;
            float* o = out + (size_t)cob * HW + (gyo << 7) + xx;
#pragma unroll
            for (int r = 0; r < 4; ++r)
                o[(size_t)r * HW] = acc[i][j][r] + cb[cob + r];
        }
    }
}

extern "C" void kernel_launch(void* const* d_in, const int* in_sizes, int n_in,
                              void* d_out, int out_size, void* d_ws, size_t ws_size,
                              hipStream_t stream) {
    const float* x    = (const float*)d_in[0];
    const float* wsp  = (const float*)d_in[1];
    const float* wpw  = (const float*)d_in[2];
    const float* bias = (const float*)d_in[3];
    const float* cw   = (const float*)d_in[4];
    const float* cb   = (const float*)d_in[5];
    float* out = (float*)d_out;

    char* ws = (char*)d_ws;
    u16*   ysT  = (u16*)ws;                        // 16,777,216 B
    u16*   wT   = (u16*)(ws + 16777216);           //  4,718,592 B
    float* mean = (float*)(ws + 21495808);         //      8,192 B
    float* rstd = (float*)(ws + 21504000);         //      8,192 B
    float* wf   = (float*)(ws + 21512192);         //     73,728 B
    float* bf   = (float*)(ws + 21585920);         //      2,048 B

    stats_kernel<<<NBC, 256, 0, stream>>>(x, mean, rstd);
    weff_kernel<<<(4 * 128 * 4 * 9 + 255) / 256, 256, 0, stream>>>(wsp, wpw, rstd, wf);
    bias_fold<<<2, 256, 0, stream>>>(wf, bias, mean, bf);
    wpack_kernel<<<512, 256, 0, stream>>>(cw, wT);
    midconv_fused<<<dim3(128, 4), 512, 0, stream>>>(x, wf, bf, ysT);
    finalconv_mfma<<<512, 256, 0, stream>>>(ysT, wT, cb, out);
}

// Round 8
// 356.327 us; speedup vs baseline: 8.9160x; 1.0282x over previous
//
#include <hip/hip_runtime.h>
#include <hip/hip_bf16.h>

// AdaConv2d: instance-norm (folded into weights) -> per-sample grouped 3x3
// (+fused pointwise) writing ysT[pix][ci] bf16 directly -> final dense
// 512->512 3x3 conv as bf16 MFMA implicit GEMM.
// B=4, C=512, H=W=128. Final conv: M=co(512), N=pix(16384), K=ci(512)x9taps.

typedef unsigned short u16;
typedef __attribute__((ext_vector_type(8))) short bf16x8;
typedef __attribute__((ext_vector_type(4))) float f32x4;

#define HW 16384
#define NBC 2048

__device__ __forceinline__ int refl(int i) {
    return i < 0 ? -i : (i > 127 ? 254 - i : i);
}

__device__ __forceinline__ u16 f2bf(float f) {
    union { float f; unsigned u; } x; x.f = f;
    unsigned r = x.u + 0x7fffu + ((x.u >> 16) & 1u);
    return (u16)(r >> 16);
}

__device__ __forceinline__ void load_lds16(const u16* g, u16* l) {
    __builtin_amdgcn_global_load_lds(
        (const __attribute__((address_space(1))) unsigned int*)g,
        (__attribute__((address_space(3))) unsigned int*)l, 16, 0, 0);
}

__device__ __forceinline__ void load_lds16f(const float* g, float* l) {
    __builtin_amdgcn_global_load_lds(
        (const __attribute__((address_space(1))) unsigned int*)g,
        (__attribute__((address_space(3))) unsigned int*)l, 16, 0, 0);
}

__device__ __forceinline__ void load_lds4(const float* g, float* l) {
    __builtin_amdgcn_global_load_lds(
        (const __attribute__((address_space(1))) unsigned int*)g,
        (__attribute__((address_space(3))) unsigned int*)l, 4, 0, 0);
}

// ---------------- Kernel A: per-(b,c) mean / rstd -------------------------
__global__ __launch_bounds__(256) void stats_kernel(
        const float* __restrict__ x, float* __restrict__ mean,
        float* __restrict__ rstd) {
    int bc = blockIdx.x;
    const float4* p4 = (const float4*)(x + (size_t)bc * HW);
    float s = 0.f, ss = 0.f;
    for (int i = threadIdx.x; i < HW / 4; i += 256) {
        float4 v = p4[i];
        s  += v.x + v.y + v.z + v.w;
        ss += v.x * v.x + v.y * v.y + v.z * v.z + v.w * v.w;
    }
    for (int o = 32; o >= 1; o >>= 1) {
        s  += __shfl_down(s, o);
        ss += __shfl_down(ss, o);
    }
    __shared__ float sm[4], sm2[4];
    int wid = threadIdx.x >> 6, lane = threadIdx.x & 63;
    if (lane == 0) { sm[wid] = s; sm2[wid] = ss; }
    __syncthreads();
    if (threadIdx.x == 0) {
        float S = sm[0] + sm[1] + sm[2] + sm[3];
        float SS = sm2[0] + sm2[1] + sm2[2] + sm2[3];
        float m = S * (1.f / HW);
        float var = SS * (1.f / HW) - m * m;
        mean[bc] = m;
        rstd[bc] = rsqrtf(var + 1e-5f);
    }
}

// ---------------- Kernel B: effective grouped weights, rstd-folded --------
// wf[b,g,c,k] = rstd[b,g*4+c] * sum_m wp[b,g,m] * ws[b,g*4+m,c,k]
__global__ __launch_bounds__(256) void weff_kernel(
        const float* __restrict__ wsp, const float* __restrict__ wpw,
        const float* __restrict__ rstd, float* __restrict__ wf) {
    int idx = blockIdx.x * 256 + threadIdx.x;
    if (idx >= 4 * 128 * 4 * 9) return;
    int k = idx % 9;
    int c = (idx / 9) & 3;
    int g = (idx / 36) & 127;
    int b = idx / 4608;
    float acc = 0.f;
#pragma unroll
    for (int m = 0; m < 4; ++m) {
        acc += wpw[(b * 128 + g) * 4 + m] *
               wsp[(((size_t)b * 512 + g * 4 + m) * 4 + c) * 9 + k];
    }
    wf[idx] = acc * rstd[(b << 9) + (g << 2) + c];
}

// ---------------- Kernel B2: folded bias ----------------------------------
__global__ __launch_bounds__(256) void bias_fold(
        const float* __restrict__ wf, const float* __restrict__ bias,
        const float* __restrict__ mean, float* __restrict__ bf) {
    int bg = blockIdx.x * 256 + threadIdx.x;
    if (bg >= 512) return;
    float s = bias[bg];
    const float* w = wf + bg * 36;
    const float* m = mean + (bg << 2);
#pragma unroll
    for (int j = 0; j < 36; ++j) s -= w[j] * m[j / 9];
    bf[bg] = s;
}

// ---------------- Kernel W: pack conv_w -> wT[tap][co][ci] bf16 -----------
__global__ __launch_bounds__(256) void wpack_kernel(
        const float* __restrict__ cw, u16* __restrict__ wT) {
    __shared__ float s[4608];
    int t = threadIdx.x, co = blockIdx.x;
    const float* src = cw + (size_t)co * 4608;
    for (int i = t; i < 4608; i += 256) s[i] = src[i];
    __syncthreads();
#pragma unroll
    for (int tap = 0; tap < 9; ++tap) {
        u16* dst = &wT[((size_t)(tap << 9) + co) * 512];
        dst[t]       = f2bf(s[t * 9 + tap]);
        dst[t + 256] = f2bf(s[(t + 256) * 9 + tap]);
    }
}

// ---------------- Kernel C: fused norm+grouped conv -> ysT bf16 -----------
__global__ __launch_bounds__(512) void midconv_fused(
        const float* __restrict__ x, const float* __restrict__ wf,
        const float* __restrict__ bf, u16* __restrict__ ysT) {
    __shared__ float mid[2][2560];     // [buf][ch*160 + r*16 + j]  20.5 KB
    __shared__ float halo[2][320];     // [buf][side*160 + ch*10 + r] 2.5 KB
    __shared__ u16 outb[128 * 72];     // [pix][64ch + pad]          18.4 KB
    __shared__ float s_w[4608];        // all 128 groups x 36        18.4 KB
    __shared__ float s_b[128];
    int t = threadIdx.x;
    int b = blockIdx.y;
    int x0 = (blockIdx.x & 7) << 4, y0 = (blockIdx.x >> 3) << 3;

    for (int i = t; i < 4608; i += 512) s_w[i] = wf[b * 4608 + i];
    if (t < 128) s_b[t] = bf[(b << 7) + t];

    int smid0, smid1, shalo;
    {
        int ch = t / 40, rem = t - ch * 40;
        int r = rem >> 2, j = rem & 3;
        smid0 = (ch << 14) + (refl(y0 + r - 1) << 7) + x0 + (j << 2);
        int i1 = t + 512 < 640 ? t + 512 : 0;
        ch = i1 / 40; rem = i1 - ch * 40; r = rem >> 2; j = rem & 3;
        smid1 = (ch << 14) + (refl(y0 + r - 1) << 7) + x0 + (j << 2);
        int ih = t < 320 ? t : 0;
        int side = ih >= 160;
        int hh = side ? ih - 160 : ih;
        ch = hh / 10; r = hh - ch * 10;
        int col = side ? refl(x0 + 16) : refl(x0 - 1);
        shalo = (ch << 14) + (refl(y0 + r - 1) << 7) + col;
    }

    int gq = t >> 7;
    int rem = t & 127;
    int py = rem >> 4, px = rem & 15;

    {
        const float* xq = x + ((size_t)(b << 9) << 14);
        load_lds16f(xq + smid0, &mid[0][t * 4]);
        if (t < 128) load_lds16f(xq + smid1, &mid[0][(512 + t) * 4]);
        if (t < 320) load_lds4(xq + shalo, &halo[0][t]);
    }

    for (int q = 0; q < 32; ++q) {
        __syncthreads();
        if (q == 16) {
            for (int i = t; i < 1024; i += 512) {
                int pix = i >> 3, seg = i & 7;
                bf16x8 v = *(const bf16x8*)&outb[pix * 72 + (seg << 3)];
                int ppy = pix >> 4, ppx = pix & 15;
                size_t gp = (size_t)(((y0 + ppy) << 7) + x0 + ppx);
                *(bf16x8*)&ysT[gp * 512 + (b << 7) + (seg << 3)] = v;
            }
            __syncthreads();
        }
        int cur = q & 1;
        if (q < 31) {
            const float* xq = x + ((size_t)((b << 9) + ((q + 1) << 4)) << 14);
            load_lds16f(xq + smid0, &mid[cur ^ 1][t * 4]);
            if (t < 128) load_lds16f(xq + smid1, &mid[cur ^ 1][(512 + t) * 4]);
            if (t < 320) load_lds4(xq + shalo, &halo[cur ^ 1][t]);
        }
        int group = (q << 2) + gq;
        float acc = s_b[group];
        const float* wq = &s_w[group * 36];
#pragma unroll
        for (int c = 0; c < 4; ++c) {
            const float* tp  = &mid[cur][(gq * 4 + c) * 160];
            const float* hlc = &halo[cur][(gq * 4 + c) * 10];
            const float* hrc = &halo[cur][160 + (gq * 4 + c) * 10];
#pragma unroll
            for (int kh = 0; kh < 3; ++kh) {
                int row = py + kh;
                const float* rp = tp + row * 16;
                float m0 = (px == 0)  ? hlc[row] : rp[px - 1];
                float m1 = rp[px];
                float m2 = (px == 15) ? hrc[row] : rp[px + 1];
                acc += wq[c * 9 + kh * 3 + 0] * m0 +
                       wq[c * 9 + kh * 3 + 1] * m1 +
                       wq[c * 9 + kh * 3 + 2] * m2;
            }
        }
        outb[(py * 16 + px) * 72 + (group & 63)] = f2bf(acc);
    }
    __syncthreads();
    for (int i = t; i < 1024; i += 512) {
        int pix = i >> 3, seg = i & 7;
        bf16x8 v = *(const bf16x8*)&outb[pix * 72 + (seg << 3)];
        int ppy = pix >> 4, ppx = pix & 15;
        size_t gp = (size_t)(((y0 + ppy) << 7) + x0 + ppx);
        *(bf16x8*)&ysT[gp * 512 + (b << 7) + 64 + (seg << 3)] = v;
    }
}

// ---------------- Kernel D: final conv via MFMA ---------------------------
// Block: 64 co x 256 pix (2 image rows), 256 thr (4 waves), wave = 64x64.
// All staging/global addresses hoisted out of the K-loop (affine in ci0);
// a-fragment LDS bases hoisted (tap becomes ds_read offset immediate).
__global__ __launch_bounds__(256, 2) void finalconv_mfma(
        const u16* __restrict__ ysT, const u16* __restrict__ wT,
        const float* __restrict__ cb, float* __restrict__ out) {
    __shared__ u16 lds_ys[528 * 32];   // chunk-swizzled, 33 KB
    __shared__ u16 lds_wt[576 * 32];   // swizzled, 36.9 KB
    int t = threadIdx.x;
    int w = t >> 6, l = t & 63;
    int m = l & 15, q = l >> 4;
    int bid = blockIdx.x;
    int swz = ((bid & 7) << 6) + (bid >> 3);
    int co0 = (swz & 7) << 6;
    int y0 = (swz >> 3) << 1;
    int tr = w >> 1, xw = (w & 1) * 64;

    // ---- hoisted staging source offsets (u16 elements, add ci0 per step)
    int ago_ys[9], ago_wt[9];
#pragma unroll
    for (int k = 0; k < 9; ++k) {
        int i = w + 4 * k;
        int i2 = i < 33 ? i : 0;
        int s = i2 * 64 + l;
        int p = s >> 2, c = s & 3;
        int pc = p > 519 ? 519 : p;
        int hr = (pc * 1009) >> 17;     // pc / 130
        int hc = pc - hr * 130;
        int gy = refl(y0 + hr - 1), gx = refl(hc - 1);
        ago_ys[k] = ((gy << 7) + gx) * 512 + (c ^ ((p >> 1) & 3)) * 8;

        int s2 = i * 64 + l;            // i < 36 always
        int row = s2 >> 2, c2 = s2 & 3;
        int tap = row >> 6, co_l = row & 63;
        ago_wt[k] = ((tap << 9) + co0 + co_l) * 512 + (c2 ^ ((co_l >> 1) & 3)) * 8;
    }

    // ---- hoisted compute-side LDS bases
    const u16* ap[4];
#pragma unroll
    for (int i = 0; i < 4; ++i) {
        int co_l = i * 16 + m;
        ap[i] = &lds_wt[co_l * 32 + (q ^ ((co_l >> 1) & 3)) * 8];
    }
    int P[4];
#pragma unroll
    for (int j = 0; j < 4; ++j) P[j] = tr * 130 + xw + j * 16 + m;

    f32x4 acc[4][4];
#pragma unroll
    for (int i = 0; i < 4; ++i)
#pragma unroll
        for (int j = 0; j < 4; ++j) acc[i][j] = (f32x4){0.f, 0.f, 0.f, 0.f};

    for (int ci0 = 0; ci0 < 512; ci0 += 32) {
        __syncthreads();
        // ---- stage (addresses precomputed; only +ci0 per step)
#pragma unroll
        for (int k = 0; k < 8; ++k)
            load_lds16(ysT + ago_ys[k] + ci0, &lds_ys[(w + 4 * k) * 512]);
        if (w == 0)
            load_lds16(ysT + ago_ys[8] + ci0, &lds_ys[32 * 512]);
#pragma unroll
        for (int k = 0; k < 9; ++k)
            load_lds16(wT + ago_wt[k] + ci0, &lds_wt[(w + 4 * k) * 512]);
        __syncthreads();
        // ---- compute: 9 taps x 4x4 fragments
#pragma unroll
        for (int tap = 0; tap < 9; ++tap) {
            const int dyi = tap / 3, dxi = tap % 3;
            bf16x8 a[4], b[4];
#pragma unroll
            for (int i = 0; i < 4; ++i)
                a[i] = *(const bf16x8*)(ap[i] + tap * 2048);
#pragma unroll
            for (int j = 0; j < 4; ++j) {
                int p = P[j] + dyi * 130 + dxi;
                b[j] = *(const bf16x8*)&lds_ys[(p << 5) + ((q ^ ((p >> 1) & 3)) << 3)];
            }
#pragma unroll
            for (int i = 0; i < 4; ++i)
#pragma unroll
                for (int j = 0; j < 4; ++j)
                    acc[i][j] = __builtin_amdgcn_mfma_f32_16x16x32_bf16(
                        a[i], b[j], acc[i][j], 0, 0, 0);
        }
    }
    int gyo = y0 + tr;
#pragma unroll
    for (int i = 0; i < 4; ++i) {
        int cob = co0 + i * 16 + q * 4;
#pragma unroll
        for (int j = 0; j < 4; ++j) {
            int xx = xw + j * 16 + m;
            float* o = out + (size_t)cob * HW + (gyo << 7) + xx;
#pragma unroll
            for (int r = 0; r < 4; ++r)
                o[(size_t)r * HW] = acc[i][j][r] + cb[cob + r];
        }
    }
}

extern "C" void kernel_launch(void* const* d_in, const int* in_sizes, int n_in,
                              void* d_out, int out_size, void* d_ws, size_t ws_size,
                              hipStream_t stream) {
    const float* x    = (const float*)d_in[0];
    const float* wsp  = (const float*)d_in[1];
    const float* wpw  = (const float*)d_in[2];
    const float* bias = (const float*)d_in[3];
    const float* cw   = (const float*)d_in[4];
    const float* cb   = (const float*)d_in[5];
    float* out = (float*)d_out;

    char* ws = (char*)d_ws;
    u16*   ysT  = (u16*)ws;                        // 16,777,216 B
    u16*   wT   = (u16*)(ws + 16777216);           //  4,718,592 B
    float* mean = (float*)(ws + 21495808);         //      8,192 B
    float* rstd = (float*)(ws + 21504000);         //      8,192 B
    float* wf   = (float*)(ws + 21512192);         //     73,728 B
    float* bf   = (float*)(ws + 21585920);         //      2,048 B

    stats_kernel<<<NBC, 256, 0, stream>>>(x, mean, rstd);
    weff_kernel<<<(4 * 128 * 4 * 9 + 255) / 256, 256, 0, stream>>>(wsp, wpw, rstd, wf);
    bias_fold<<<2, 256, 0, stream>>>(wf, bias, mean, bf);
    wpack_kernel<<<512, 256, 0, stream>>>(cw, wT);
    midconv_fused<<<dim3(128, 4), 512, 0, stream>>>(x, wf, bf, ysT);
    finalconv_mfma<<<512, 256, 0, stream>>>(ysT, wT, cb, out);
}

// Round 9
// 355.463 us; speedup vs baseline: 8.9376x; 1.0024x over previous
//
#include <hip/hip_runtime.h>
#include <hip/hip_bf16.h>

// AdaConv2d: instance-norm (folded into weights) -> per-sample grouped 3x3
// (+fused pointwise) writing ysT[pix][ci] bf16 directly -> final dense
// 512->512 3x3 conv as bf16 MFMA implicit GEMM.
// B=4, C=512, H=W=128. Final conv: M=co(512), N=pix(16384), K=ci(512)x9taps.

typedef unsigned short u16;
typedef __attribute__((ext_vector_type(8))) short bf16x8;
typedef __attribute__((ext_vector_type(4))) float f32x4;

#define HW 16384
#define NBC 2048

__device__ __forceinline__ int refl(int i) {
    return i < 0 ? -i : (i > 127 ? 254 - i : i);
}

__device__ __forceinline__ u16 f2bf(float f) {
    union { float f; unsigned u; } x; x.f = f;
    unsigned r = x.u + 0x7fffu + ((x.u >> 16) & 1u);
    return (u16)(r >> 16);
}

__device__ __forceinline__ void load_lds16(const u16* g, u16* l) {
    __builtin_amdgcn_global_load_lds(
        (const __attribute__((address_space(1))) unsigned int*)g,
        (__attribute__((address_space(3))) unsigned int*)l, 16, 0, 0);
}

__device__ __forceinline__ void load_lds16f(const float* g, float* l) {
    __builtin_amdgcn_global_load_lds(
        (const __attribute__((address_space(1))) unsigned int*)g,
        (__attribute__((address_space(3))) unsigned int*)l, 16, 0, 0);
}

__device__ __forceinline__ void load_lds4(const float* g, float* l) {
    __builtin_amdgcn_global_load_lds(
        (const __attribute__((address_space(1))) unsigned int*)g,
        (__attribute__((address_space(3))) unsigned int*)l, 4, 0, 0);
}

// ---------------- Kernel A: per-(b,c) mean / rstd -------------------------
__global__ __launch_bounds__(256) void stats_kernel(
        const float* __restrict__ x, float* __restrict__ mean,
        float* __restrict__ rstd) {
    int bc = blockIdx.x;
    const float4* p4 = (const float4*)(x + (size_t)bc * HW);
    float s = 0.f, ss = 0.f;
    for (int i = threadIdx.x; i < HW / 4; i += 256) {
        float4 v = p4[i];
        s  += v.x + v.y + v.z + v.w;
        ss += v.x * v.x + v.y * v.y + v.z * v.z + v.w * v.w;
    }
    for (int o = 32; o >= 1; o >>= 1) {
        s  += __shfl_down(s, o);
        ss += __shfl_down(ss, o);
    }
    __shared__ float sm[4], sm2[4];
    int wid = threadIdx.x >> 6, lane = threadIdx.x & 63;
    if (lane == 0) { sm[wid] = s; sm2[wid] = ss; }
    __syncthreads();
    if (threadIdx.x == 0) {
        float S = sm[0] + sm[1] + sm[2] + sm[3];
        float SS = sm2[0] + sm2[1] + sm2[2] + sm2[3];
        float m = S * (1.f / HW);
        float var = SS * (1.f / HW) - m * m;
        mean[bc] = m;
        rstd[bc] = rsqrtf(var + 1e-5f);
    }
}

// ---------------- Kernel B: fused effective weights + folded bias ---------
// One wave per (b,g). wf[bg,c,k] = rstd*Σ_m wp·ws; bf[bg] = bias − Σ wf·mean.
__global__ __launch_bounds__(64) void weff_bias_kernel(
        const float* __restrict__ wsp, const float* __restrict__ wpw,
        const float* __restrict__ rstd, const float* __restrict__ mean,
        const float* __restrict__ bias, float* __restrict__ wf,
        float* __restrict__ bf) {
    int bg = blockIdx.x;               // 0..511 = b*128+g
    int b = bg >> 7, g = bg & 127;
    int t = threadIdx.x;
    float contrib = 0.f;
    if (t < 36) {
        int c = t / 9, k = t - c * 9;
        float acc = 0.f;
#pragma unroll
        for (int m = 0; m < 4; ++m)
            acc += wpw[bg * 4 + m] *
                   wsp[(((size_t)(b << 9) + (g << 2) + m) * 4 + c) * 9 + k];
        float v = acc * rstd[(b << 9) + (g << 2) + c];
        wf[bg * 36 + t] = v;
        contrib = v * mean[(b << 9) + (g << 2) + c];
    }
    for (int o = 32; o >= 1; o >>= 1) contrib += __shfl_down(contrib, o);
    if (t == 0) bf[bg] = bias[bg] - contrib;
}

// ---------------- Kernel W: pack conv_w -> wT[tap][co][ci] bf16 -----------
__global__ __launch_bounds__(256) void wpack_kernel(
        const float* __restrict__ cw, u16* __restrict__ wT) {
    __shared__ float s[4608];
    int t = threadIdx.x, co = blockIdx.x;
    const float* src = cw + (size_t)co * 4608;
    for (int i = t; i < 4608; i += 256) s[i] = src[i];
    __syncthreads();
#pragma unroll
    for (int tap = 0; tap < 9; ++tap) {
        u16* dst = &wT[((size_t)(tap << 9) + co) * 512];
        dst[t]       = f2bf(s[t * 9 + tap]);
        dst[t + 256] = f2bf(s[(t + 256) * 9 + tap]);
    }
}

// ---------------- Kernel C: fused norm+grouped conv -> ysT bf16 -----------
// Block = (8x16 tile, quad-set of 8, batch); grid 2048; 512 thr; 8 iters.
// Double-buffered width-16 staging (lane-linear); outb f32 [pix][33]
// (conflict-free writes); one coalesced bf16x8 flush at the end.
__global__ __launch_bounds__(512) void midconv_fused(
        const float* __restrict__ x, const float* __restrict__ wf,
        const float* __restrict__ bf, u16* __restrict__ ysT) {
    __shared__ float mid[2][2560];     // [buf][ch*160 + r*16 + j]   20.5 KB
    __shared__ float halo[2][320];     // [buf][side*160 + ch*10 + r] 2.5 KB
    __shared__ float outb[128 * 33];   // [pix][32col + pad]         16.9 KB
    __shared__ float s_w[1152];        // 32 groups x 36              4.6 KB
    __shared__ float s_b[32];
    int t = threadIdx.x;
    int qr = blockIdx.y;               // quad-set 0..3 (8 quads = 128 ch)
    int b = blockIdx.z;
    int x0 = (blockIdx.x & 7) << 4, y0 = (blockIdx.x >> 3) << 3;

    for (int i = t; i < 1152; i += 512) s_w[i] = wf[b * 4608 + qr * 1152 + i];
    if (t < 32) s_b[t] = bf[(b << 7) + (qr << 5) + t];

    // per-lane global source offsets (constant over q; channel-relative)
    int smid0, smid1, shalo;
    {
        int ch = t / 40, rem = t - ch * 40;
        int r = rem >> 2, j = rem & 3;
        smid0 = (ch << 14) + (refl(y0 + r - 1) << 7) + x0 + (j << 2);
        int i1 = t + 512 < 640 ? t + 512 : 0;
        ch = i1 / 40; rem = i1 - ch * 40; r = rem >> 2; j = rem & 3;
        smid1 = (ch << 14) + (refl(y0 + r - 1) << 7) + x0 + (j << 2);
        int ih = t < 320 ? t : 0;
        int side = ih >= 160;
        int hh = side ? ih - 160 : ih;
        ch = hh / 10; r = hh - ch * 10;
        int col = side ? refl(x0 + 16) : refl(x0 - 1);
        shalo = (ch << 14) + (refl(y0 + r - 1) << 7) + col;
    }

    int gq = t >> 7;                   // group within quad (0..3)
    int rem = t & 127;
    int py = rem >> 4, px = rem & 15;
    int ch_base = (b << 9) + (qr << 7);

    // prologue: stage q=0 into buf 0
    {
        const float* xq = x + ((size_t)ch_base << 14);
        load_lds16f(xq + smid0, &mid[0][t * 4]);
        if (t < 128) load_lds16f(xq + smid1, &mid[0][(512 + t) * 4]);
        if (t < 320) load_lds4(xq + shalo, &halo[0][t]);
    }

    for (int q = 0; q < 8; ++q) {
        __syncthreads();               // drains vmcnt: buf[q&1] ready
        int cur = q & 1;
        if (q < 7) {                   // issue next-tile loads (overlap)
            const float* xq = x + ((size_t)(ch_base + ((q + 1) << 4)) << 14);
            load_lds16f(xq + smid0, &mid[cur ^ 1][t * 4]);
            if (t < 128) load_lds16f(xq + smid1, &mid[cur ^ 1][(512 + t) * 4]);
            if (t < 320) load_lds4(xq + shalo, &halo[cur ^ 1][t]);
        }
        int col = (q << 2) + gq;       // 0..31 within this quad-set
        float acc = s_b[col];
        const float* wq = &s_w[col * 36];
#pragma unroll
        for (int c = 0; c < 4; ++c) {
            const float* tp  = &mid[cur][(gq * 4 + c) * 160];
            const float* hlc = &halo[cur][(gq * 4 + c) * 10];
            const float* hrc = &halo[cur][160 + (gq * 4 + c) * 10];
#pragma unroll
            for (int kh = 0; kh < 3; ++kh) {
                int row = py + kh;
                const float* rp = tp + row * 16;
                float m0 = (px == 0)  ? hlc[row] : rp[px - 1];
                float m1 = rp[px];
                float m2 = (px == 15) ? hrc[row] : rp[px + 1];
                acc += wq[c * 9 + kh * 3 + 0] * m0 +
                       wq[c * 9 + kh * 3 + 1] * m1 +
                       wq[c * 9 + kh * 3 + 2] * m2;
            }
        }
        outb[(py * 16 + px) * 33 + col] = acc;   // bank (pix+col)%32: 2-way
    }
    __syncthreads();
    // flush: 128 pix x 4 segs of 8 ch; one bf16x8 store per thread
    {
        int pix = t >> 2, seg = t & 3;
        const float* src = &outb[pix * 33 + (seg << 3)];
        bf16x8 v;
#pragma unroll
        for (int j = 0; j < 8; ++j) v[j] = (short)f2bf(src[j]);
        int ppy = pix >> 4, ppx = pix & 15;
        size_t gp = (size_t)(((y0 + ppy) << 7) + x0 + ppx);
        *(bf16x8*)&ysT[gp * 512 + (b << 7) + (qr << 5) + (seg << 3)] = v;
    }
}

// ---------------- Kernel D: final conv via MFMA ---------------------------
// Block: 64 co x 256 pix (2 image rows), 256 thr (4 waves), wave = 64x64.
// All staging/global addresses hoisted out of the K-loop (affine in ci0);
// a-fragment LDS bases hoisted (tap becomes ds_read offset immediate).
__global__ __launch_bounds__(256, 2) void finalconv_mfma(
        const u16* __restrict__ ysT, const u16* __restrict__ wT,
        const float* __restrict__ cb, float* __restrict__ out) {
    __shared__ u16 lds_ys[528 * 32];   // chunk-swizzled, 33 KB
    __shared__ u16 lds_wt[576 * 32];   // swizzled, 36.9 KB
    int t = threadIdx.x;
    int w = t >> 6, l = t & 63;
    int m = l & 15, q = l >> 4;
    int bid = blockIdx.x;
    int swz = ((bid & 7) << 6) + (bid >> 3);
    int co0 = (swz & 7) << 6;
    int y0 = (swz >> 3) << 1;
    int tr = w >> 1, xw = (w & 1) * 64;

    // ---- hoisted staging source offsets (u16 elements, add ci0 per step)
    int ago_ys[9], ago_wt[9];
#pragma unroll
    for (int k = 0; k < 9; ++k) {
        int i = w + 4 * k;
        int i2 = i < 33 ? i : 0;
        int s = i2 * 64 + l;
        int p = s >> 2, c = s & 3;
        int pc = p > 519 ? 519 : p;
        int hr = (pc * 1009) >> 17;     // pc / 130
        int hc = pc - hr * 130;
        int gy = refl(y0 + hr - 1), gx = refl(hc - 1);
        ago_ys[k] = ((gy << 7) + gx) * 512 + (c ^ ((p >> 1) & 3)) * 8;

        int s2 = i * 64 + l;            // i < 36 always
        int row = s2 >> 2, c2 = s2 & 3;
        int tap = row >> 6, co_l = row & 63;
        ago_wt[k] = ((tap << 9) + co0 + co_l) * 512 + (c2 ^ ((co_l >> 1) & 3)) * 8;
    }

    // ---- hoisted compute-side LDS bases
    const u16* ap[4];
#pragma unroll
    for (int i = 0; i < 4; ++i) {
        int co_l = i * 16 + m;
        ap[i] = &lds_wt[co_l * 32 + (q ^ ((co_l >> 1) & 3)) * 8];
    }
    int P[4];
#pragma unroll
    for (int j = 0; j < 4; ++j) P[j] = tr * 130 + xw + j * 16 + m;

    f32x4 acc[4][4];
#pragma unroll
    for (int i = 0; i < 4; ++i)
#pragma unroll
        for (int j = 0; j < 4; ++j) acc[i][j] = (f32x4){0.f, 0.f, 0.f, 0.f};

    for (int ci0 = 0; ci0 < 512; ci0 += 32) {
        __syncthreads();
        // ---- stage (addresses precomputed; only +ci0 per step)
#pragma unroll
        for (int k = 0; k < 8; ++k)
            load_lds16(ysT + ago_ys[k] + ci0, &lds_ys[(w + 4 * k) * 512]);
        if (w == 0)
            load_lds16(ysT + ago_ys[8] + ci0, &lds_ys[32 * 512]);
#pragma unroll
        for (int k = 0; k < 9; ++k)
            load_lds16(wT + ago_wt[k] + ci0, &lds_wt[(w + 4 * k) * 512]);
        __syncthreads();
        // ---- compute: 9 taps x 4x4 fragments
#pragma unroll
        for (int tap = 0; tap < 9; ++tap) {
            const int dyi = tap / 3, dxi = tap % 3;
            bf16x8 a[4], b[4];
#pragma unroll
            for (int i = 0; i < 4; ++i)
                a[i] = *(const bf16x8*)(ap[i] + tap * 2048);
#pragma unroll
            for (int j = 0; j < 4; ++j) {
                int p = P[j] + dyi * 130 + dxi;
                b[j] = *(const bf16x8*)&lds_ys[(p << 5) + ((q ^ ((p >> 1) & 3)) << 3)];
            }
#pragma unroll
            for (int i = 0; i < 4; ++i)
#pragma unroll
                for (int j = 0; j < 4; ++j)
                    acc[i][j] = __builtin_amdgcn_mfma_f32_16x16x32_bf16(
                        a[i], b[j], acc[i][j], 0, 0, 0);
        }
    }
    int gyo = y0 + tr;
#pragma unroll
    for (int i = 0; i < 4; ++i) {
        int cob = co0 + i * 16 + q * 4;
#pragma unroll
        for (int j = 0; j < 4; ++j) {
            int xx = xw + j * 16 + m;
            float* o = out + (size_t)cob * HW + (gyo << 7) + xx;
#pragma unroll
            for (int r = 0; r < 4; ++r)
                o[(size_t)r * HW] = acc[i][j][r] + cb[cob + r];
        }
    }
}

extern "C" void kernel_launch(void* const* d_in, const int* in_sizes, int n_in,
                              void* d_out, int out_size, void* d_ws, size_t ws_size,
                              hipStream_t stream) {
    const float* x    = (const float*)d_in[0];
    const float* wsp  = (const float*)d_in[1];
    const float* wpw  = (const float*)d_in[2];
    const float* bias = (const float*)d_in[3];
    const float* cw   = (const float*)d_in[4];
    const float* cb   = (const float*)d_in[5];
    float* out = (float*)d_out;

    char* ws = (char*)d_ws;
    u16*   ysT  = (u16*)ws;                        // 16,777,216 B
    u16*   wT   = (u16*)(ws + 16777216);           //  4,718,592 B
    float* mean = (float*)(ws + 21495808);         //      8,192 B
    float* rstd = (float*)(ws + 21504000);         //      8,192 B
    float* wf   = (float*)(ws + 21512192);         //     73,728 B
    float* bf   = (float*)(ws + 21585920);         //      2,048 B

    stats_kernel<<<NBC, 256, 0, stream>>>(x, mean, rstd);
    weff_bias_kernel<<<512, 64, 0, stream>>>(wsp, wpw, rstd, mean, bias, wf, bf);
    wpack_kernel<<<512, 256, 0, stream>>>(cw, wT);
    midconv_fused<<<dim3(128, 4, 4), 512, 0, stream>>>(x, wf, bf, ysT);
    finalconv_mfma<<<512, 256, 0, stream>>>(ysT, wT, cb, out);
}